// Round 5
// baseline (517.792 us; speedup 1.0000x reference)
//
#include <hip/hip_runtime.h>
#include <math.h>

#define Bz 4
#define Tz 2048
#define Cz 1024
#define Hz 16
#define Dz 64
#define MTOK (Bz*Tz)   // 8192

typedef __attribute__((ext_vector_type(8))) short short8;
typedef __attribute__((ext_vector_type(4))) short short4v;
typedef __attribute__((ext_vector_type(4))) float f32x4;

typedef unsigned int u32_g __attribute__((address_space(1)));
typedef unsigned int u32_l __attribute__((address_space(3)));

__device__ __forceinline__ unsigned short f2bf(float f) {
    unsigned int u = __float_as_uint(f);
    u += 0x7fffu + ((u >> 16) & 1u);
    return (unsigned short)(u >> 16);
}
__device__ __forceinline__ float bf2f(unsigned short h) {
    return __uint_as_float((unsigned int)h << 16);
}

__device__ __forceinline__ void async_cp16(const unsigned short* g, unsigned short* l) {
    __builtin_amdgcn_global_load_lds((const u32_g*)g, (u32_l*)l, 16, 0, 0);
}

#define BARX() __builtin_amdgcn_s_barrier()
#define VMCM(n) asm volatile("s_waitcnt vmcnt(" #n ")" ::: "memory")

// ---------------- weight transpose: W[K][N] f32 -> Wt[N][K] bf16 ----------------
__global__ void transpose_w(const float* __restrict__ W, unsigned short* __restrict__ Wt,
                            int K, int N) {
    __shared__ float tile[32][33];
    int n0 = blockIdx.x * 32, k0 = blockIdx.y * 32;
    int tx = threadIdx.x, ty = threadIdx.y;   // (32, 8)
    #pragma unroll
    for (int i = 0; i < 4; i++)
        tile[ty + i * 8][tx] = W[(size_t)(k0 + ty + i * 8) * N + n0 + tx];
    __syncthreads();
    #pragma unroll
    for (int i = 0; i < 4; i++)
        Wt[(size_t)(n0 + ty + i * 8) * K + k0 + tx] = f2bf(tile[tx][ty + i * 8]);
}

// ---------------- V transpose: vtmp[B*H][T][D] -> vt[B*H][D][T] -----------------
__global__ void transpose_v(const unsigned short* __restrict__ in, unsigned short* __restrict__ out) {
    __shared__ unsigned short tile[64][68];
    const int bh = blockIdx.x;        // 0..63
    const int t0 = blockIdx.y * 64;   // 32 tiles along T
    const int tid = threadIdx.x;      // 256
    const int r4 = tid >> 4;          // 0..15
    const int c4 = tid & 15;          // 0..15
    #pragma unroll
    for (int p = 0; p < 4; p++) {
        const int r = p * 16 + r4;
        *(short4v*)&tile[r][c4 * 4] =
            *(const short4v*)&in[((size_t)bh * Tz + t0 + r) * Dz + c4 * 4];
    }
    __syncthreads();
    #pragma unroll
    for (int p = 0; p < 4; p++) {
        const int d = p * 16 + r4;
        short4v o;
        #pragma unroll
        for (int j = 0; j < 4; j++) o[j] = tile[c4 * 4 + j][d];
        *(short4v*)&out[((size_t)bh * Dz + d) * Tz + t0 + c4 * 4] = o;
    }
}

// ---------------- layernorm: fp32 in -> bf16 out ----------------
__global__ void ln_kernel(const float* __restrict__ x, const float* __restrict__ g,
                          const float* __restrict__ bb, unsigned short* __restrict__ out) {
    int tok = blockIdx.x, tid = threadIdx.x;
    const float4 v = ((const float4*)(x + (size_t)tok * Cz))[tid];
    float s = v.x + v.y + v.z + v.w;
    float sq = v.x * v.x + v.y * v.y + v.z * v.z + v.w * v.w;
    #pragma unroll
    for (int m = 1; m < 64; m <<= 1) { s += __shfl_xor(s, m); sq += __shfl_xor(sq, m); }
    __shared__ float red[8];
    int lane = tid & 63, wid = tid >> 6;
    if (!lane) { red[wid] = s; red[4 + wid] = sq; }
    __syncthreads();
    s = red[0] + red[1] + red[2] + red[3];
    sq = red[4] + red[5] + red[6] + red[7];
    float mu = s * (1.0f / Cz);
    float var = sq * (1.0f / Cz) - mu * mu;
    float rs = rsqrtf(var + 1e-5f);
    float4 gv = ((const float4*)g)[tid];
    float4 bv = ((const float4*)bb)[tid];
    short4v o;
    o[0] = f2bf((v.x - mu) * rs * gv.x + bv.x);
    o[1] = f2bf((v.y - mu) * rs * gv.y + bv.y);
    o[2] = f2bf((v.z - mu) * rs * gv.z + bv.z);
    o[3] = f2bf((v.w - mu) * rs * gv.w + bv.w);
    *(short4v*)(out + (size_t)tok * Cz + tid * 4) = o;
}

#define MODE_QKV 0
#define MODE_RESID 1
#define MODE_GELU 2

// ========== register-double-buffered pipelined GEMM, BM=256 x BN=128, BK=32 =====
// 512 thr = 8 waves (4M x 2N), wave tile 64x64. LDS: 4 slots x [A 256x32|B 128x32]
// = 96 KiB, stage depth 3. Per K-tile: ONE counted vmcnt(3) + ONE s_barrier.
// Key structure: ds_reads for tile t+1 go into register set B while MFMAs for
// tile t consume register set A -> no dependency between the read burst and the
// MFMA burst, lgkm completion needed only one iteration later (latency hidden by
// dataflow). vmcnt(3) guarantees tile t+1's staging landed (per-wave wait, then
// barrier publishes all waves); never drained to 0 except the peeled tail.
template <int MODE>
__launch_bounds__(512, 1)
__global__ void gemm_p(const unsigned short* __restrict__ A, const unsigned short* __restrict__ Bt,
                       int lda, int K, int N, const float* __restrict__ bias,
                       float* __restrict__ outf, unsigned short* __restrict__ outb,
                       const float* __restrict__ resid,
                       unsigned short* __restrict__ qo, unsigned short* __restrict__ ko,
                       unsigned short* __restrict__ vo) {
    __shared__ __align__(16) unsigned short LDS[4 * 12288];   // 96 KiB
    const int tid = threadIdx.x;
    const int lane = tid & 63;
    const int wid = tid >> 6;
    const int quad = lane >> 4, l15 = lane & 15;
    const int gm = wid >> 1, gn = wid & 1;
    const int id = blockIdx.x;
    const int rr = id >> 3;
    const int m0 = ((id & 7) * 4 + (rr & 3)) * 256;   // XCD-contiguous m-tiles
    const int n0 = (rr >> 2) * 128;
    const int NT = K >> 5;

    // staging: thread -> row tid/4 (A also +128), phys 16B-seg tid&3; global col
    // pre-swizzled (seg ^ (row>>1)&3) so linear LDS dest + swizzled read match.
    const int lseg = (tid & 3) ^ ((tid >> 3) & 3);
    const int srow = tid >> 2;
    const unsigned short* Ag0 = A + (size_t)(m0 + srow) * lda + lseg * 8;
    const unsigned short* Ag1 = A + (size_t)(m0 + 128 + srow) * lda + lseg * 8;
    const unsigned short* Bg0 = Bt + (size_t)(n0 + srow) * lda + lseg * 8;

    int offA[4], offB[4];
    #pragma unroll
    for (int mi = 0; mi < 4; mi++) {
        const int ra = gm * 64 + mi * 16 + l15;
        offA[mi] = ra * 32 + ((quad ^ ((ra >> 1) & 3)) << 3);
    }
    #pragma unroll
    for (int ni = 0; ni < 4; ni++) {
        const int rb = gn * 64 + ni * 16 + l15;
        offB[ni] = 8192 + rb * 32 + ((quad ^ ((rb >> 1) & 3)) << 3);
    }

    f32x4 acc[4][4] = {};
    short8 afA[4], bfA[4], afB[4], bfB[4];

#define STG(tt) do { \
    unsigned short* sp_ = LDS + (((unsigned)(tt)) & 3u) * 12288; \
    const size_t kof_ = (size_t)(tt) * 32; \
    async_cp16(Ag0 + kof_, sp_ + tid * 8); \
    async_cp16(Ag1 + kof_, sp_ + 4096 + tid * 8); \
    async_cp16(Bg0 + kof_, sp_ + 8192 + tid * 8); } while (0)
#define RDS(afX, bfX, tt) do { \
    const unsigned short* sp_ = LDS + (((unsigned)(tt)) & 3u) * 12288; \
    _Pragma("unroll") for (int mi = 0; mi < 4; mi++) afX[mi] = *(const short8*)(sp_ + offA[mi]); \
    _Pragma("unroll") for (int ni = 0; ni < 4; ni++) bfX[ni] = *(const short8*)(sp_ + offB[ni]); } while (0)
#define MMS(afX, bfX) do { \
    __builtin_amdgcn_s_setprio(1); \
    _Pragma("unroll") for (int mi = 0; mi < 4; mi++) \
        _Pragma("unroll") for (int ni = 0; ni < 4; ni++) \
            acc[mi][ni] = __builtin_amdgcn_mfma_f32_16x16x32_bf16(afX[mi], bfX[ni], acc[mi][ni], 0, 0, 0); \
    __builtin_amdgcn_s_setprio(0); } while (0)

    // prologue: stage tiles 0,1,2 (9 loads/wave); wait own tile0 (leave 6),
    // barrier publishes all waves' tile0 -> pre-read tile0 into set A.
    STG(0); STG(1); STG(2);
    VMCM(6);
    BARX();
    RDS(afA, bfA, 0);

    for (int t = 0; t < NT; t += 2) {
        // ---- even: compute tile t (set A), read tile t+1 (set B) ----
        if (t + 2 < NT) { VMCM(3); } else { VMCM(0); }   // t+1 landed
        BARX();
        if (t + 3 < NT) STG(t + 3);
        RDS(afB, bfB, t + 1);
        MMS(afA, bfA);
        // ---- odd: compute tile t+1 (set B), read tile t+2 (set A) ----
        if (t + 2 < NT) { VMCM(3); }                     // t+2 landed
        BARX();
        if (t + 4 < NT) STG(t + 4);
        if (t + 2 < NT) RDS(afA, bfA, t + 2);
        MMS(afB, bfB);
    }
#undef STG
#undef RDS
#undef MMS

    // epilogue: ni innermost so each output row's 128/256 B line fills in 4
    // consecutive stores (fixes 2.5x HBM write amplification seen at ni-outer).
    float bv[4];
    #pragma unroll
    for (int ni = 0; ni < 4; ni++) bv[ni] = bias[n0 + gn * 64 + ni * 16 + l15];

    if constexpr (MODE == MODE_QKV) {
        const int colb = n0 + gn * 64;          // 64-aligned -> single (which, head)
        const int which = colb >> 10;
        const int hh = (colb & 1023) >> 6;
        unsigned short* dst = (which == 0) ? qo : (which == 1) ? ko : vo;
        #pragma unroll
        for (int mi = 0; mi < 4; mi++) {
            #pragma unroll
            for (int r = 0; r < 4; r++) {
                const int row = m0 + gm * 64 + mi * 16 + quad * 4 + r;
                const int b_ = row >> 11, tt = row & 2047;
                unsigned short* rp = dst + ((size_t)(b_ * Hz + hh) * Tz + tt) * Dz;
                #pragma unroll
                for (int ni = 0; ni < 4; ni++)
                    rp[ni * 16 + l15] = f2bf(acc[mi][ni][r] + bv[ni]);
            }
        }
    } else if constexpr (MODE == MODE_RESID) {
        #pragma unroll
        for (int mi = 0; mi < 4; mi++) {
            #pragma unroll
            for (int r = 0; r < 4; r++) {
                const int row = m0 + gm * 64 + mi * 16 + quad * 4 + r;
                float* rp = outf + (size_t)row * N + n0 + gn * 64;
                const float* rr_ = resid + (size_t)row * N + n0 + gn * 64;
                #pragma unroll
                for (int ni = 0; ni < 4; ni++) {
                    const int c = ni * 16 + l15;
                    rp[c] = acc[mi][ni][r] + bv[ni] + rr_[c];
                }
            }
        }
    } else {  // MODE_GELU, tanh-form
        #pragma unroll
        for (int mi = 0; mi < 4; mi++) {
            #pragma unroll
            for (int r = 0; r < 4; r++) {
                const int row = m0 + gm * 64 + mi * 16 + quad * 4 + r;
                unsigned short* rp = outb + (size_t)row * N + n0 + gn * 64;
                #pragma unroll
                for (int ni = 0; ni < 4; ni++) {
                    float val = acc[mi][ni][r] + bv[ni];
                    float c = val * (1.0f + 0.044715f * val * val);
                    float e = __expf(1.5957691216057308f * c);
                    rp[ni * 16 + l15] = f2bf(val * e / (1.0f + e));
                }
            }
        }
    }
}

// ---------------- causal flash attention, bf16 MFMA ----------------
#define ATT_SC 0.18033688011112042f   // 0.125 * log2(e)
__launch_bounds__(256)
__global__ void attn_kernel(const unsigned short* __restrict__ qb, const unsigned short* __restrict__ kb,
                            const unsigned short* __restrict__ vt, unsigned short* __restrict__ y) {
    __shared__ __align__(16) unsigned short Klds[64 * 64];
    __shared__ __align__(16) unsigned short Vtl[64 * 64];
    __shared__ __align__(16) unsigned short Plds[4][16 * 72];
    const int tid = threadIdx.x;
    const int lane = tid & 63, wid = tid >> 6;
    const int quad = lane >> 4, l15 = lane & 15;
    const int bh = blockIdx.x & 63;
    const int qt = 15 - (int)(blockIdx.x >> 6);
    const size_t baseT = (size_t)bh * Tz;
    const size_t vbase = (size_t)bh * Dz;
    const int qb0 = qt * 128;

    short8 qf[2][2];
    {
        const unsigned short* q0p = qb + (baseT + qb0 + wid * 16 + l15) * Dz + quad * 8;
        qf[0][0] = *(const short8*)q0p;
        qf[0][1] = *(const short8*)(q0p + 32);
        const unsigned short* q1p = q0p + (size_t)64 * Dz;
        qf[1][0] = *(const short8*)q1p;
        qf[1][1] = *(const short8*)(q1p + 32);
    }

    f32x4 o[2][4] = {};
    float lsum[2][4] = {{0.f,0.f,0.f,0.f},{0.f,0.f,0.f,0.f}};

    const int srow = lane >> 3;
    const int swz = ((lane & 7) ^ srow) * 8;
    const unsigned short* kg0 = kb + (baseT + wid * 8 + srow) * Dz + swz;
    const unsigned short* kg1 = kg0 + (size_t)32 * Dz;
    const unsigned short* vg0 = vt + (vbase + wid * 8 + srow) * Tz + swz;
    const unsigned short* vg1 = vg0 + (size_t)32 * Tz;
    unsigned short* kl0 = &Klds[wid * 512 + lane * 8];
    unsigned short* kl1 = kl0 + 2048;
    unsigned short* vl0 = &Vtl[wid * 512 + lane * 8];
    unsigned short* vl1 = vl0 + 2048;

    const int nchunk = 2 * qt + 2;

    for (int ci = 0; ci < nchunk; ci++) {
        const int k0 = ci * 64;
        async_cp16(kg0 + (size_t)k0 * Dz, kl0);
        async_cp16(kg1 + (size_t)k0 * Dz, kl1);
        async_cp16(vg0 + k0, vl0);
        async_cp16(vg1 + k0, vl1);
        __syncthreads();

        #pragma unroll
        for (int t = 0; t < 2; t++) {
            if (t == 0 && ci == nchunk - 1) continue;
            const bool diag = (ci == nchunk - 2 + t);

            f32x4 s[4];
            #pragma unroll
            for (int c = 0; c < 4; c++) {
                const int rk = c * 16 + l15;
                short8 kf0 = *(const short8*)&Klds[rk * 64 + ((quad ^ (rk & 7)) * 8)];
                short8 kf1 = *(const short8*)&Klds[rk * 64 + (((quad + 4) ^ (rk & 7)) * 8)];
                f32x4 z = {};
                z = __builtin_amdgcn_mfma_f32_16x16x32_bf16(qf[t][0], kf0, z, 0, 0, 0);
                s[c] = __builtin_amdgcn_mfma_f32_16x16x32_bf16(qf[t][1], kf1, z, 0, 0, 0);
            }
            const int qr = qb0 + t * 64 + wid * 16 + quad * 4;
            #pragma unroll
            for (int c = 0; c < 4; c++)
                #pragma unroll
                for (int r = 0; r < 4; r++) {
                    float p = exp2f(s[c][r] * ATT_SC);
                    if (diag) {
                        int key = k0 + c * 16 + l15;
                        p = (key <= qr + r) ? p : 0.f;
                    }
                    s[c][r] = p;
                    lsum[t][r] += p;
                }
            unsigned short* P = Plds[wid];
            #pragma unroll
            for (int c = 0; c < 4; c++)
                #pragma unroll
                for (int r = 0; r < 4; r++)
                    P[(quad * 4 + r) * 72 + c * 16 + l15] = f2bf(s[c][r]);
            short8 pf0 = *(const short8*)&P[l15 * 72 + quad * 8];
            short8 pf1 = *(const short8*)&P[l15 * 72 + 32 + quad * 8];
            #pragma unroll
            for (int nc = 0; nc < 4; nc++) {
                const int rv = nc * 16 + l15;
                short8 vf0 = *(const short8*)&Vtl[rv * 64 + ((quad ^ (rv & 7)) * 8)];
                short8 vf1 = *(const short8*)&Vtl[rv * 64 + (((quad + 4) ^ (rv & 7)) * 8)];
                o[t][nc] = __builtin_amdgcn_mfma_f32_16x16x32_bf16(pf0, vf0, o[t][nc], 0, 0, 0);
                o[t][nc] = __builtin_amdgcn_mfma_f32_16x16x32_bf16(pf1, vf1, o[t][nc], 0, 0, 0);
            }
        }
        __syncthreads();
    }

    const int b_ = bh >> 4, hh = bh & 15;
    #pragma unroll
    for (int t = 0; t < 2; t++)
        #pragma unroll
        for (int r = 0; r < 4; r++) {
            float ls = lsum[t][r];
            #pragma unroll
            for (int m = 1; m < 16; m <<= 1) ls += __shfl_xor(ls, m);
            float inv = 1.0f / ls;
            size_t tok = (size_t)qb0 + t * 64 + wid * 16 + quad * 4 + r;
            unsigned short* yr = y + ((size_t)b_ * Tz + tok) * Cz + hh * Dz;
            #pragma unroll
            for (int nc = 0; nc < 4; nc++)
                yr[nc * 16 + l15] = f2bf(o[t][nc][r] * inv);
        }
}

extern "C" void kernel_launch(void* const* d_in, const int* in_sizes, int n_in,
                              void* d_out, int out_size, void* d_ws, size_t ws_size,
                              hipStream_t stream) {
    const float* x    = (const float*)d_in[0];
    const float* ln1g = (const float*)d_in[1];
    const float* ln1b = (const float*)d_in[2];
    const float* Wqkv = (const float*)d_in[3];
    const float* bqkv = (const float*)d_in[4];
    const float* Wo   = (const float*)d_in[5];
    const float* bo   = (const float*)d_in[6];
    const float* ln2g = (const float*)d_in[7];
    const float* ln2b = (const float*)d_in[8];
    const float* Wfc  = (const float*)d_in[9];
    const float* bfc  = (const float*)d_in[10];
    const float* Wpr  = (const float*)d_in[11];
    const float* bpr  = (const float*)d_in[12];
    float* out = (float*)d_out;

    char* ws = (char*)d_ws;
    size_t off = 0;
    auto alloc = [&](size_t bytes) { void* p = ws + off; off += (bytes + 255) & ~(size_t)255; return p; };
    unsigned short* wqkv_t = (unsigned short*)alloc((size_t)3072 * 1024 * 2);
    unsigned short* wo_t   = (unsigned short*)alloc((size_t)1024 * 1024 * 2);
    unsigned short* wfc_t  = (unsigned short*)alloc((size_t)4096 * 1024 * 2);
    unsigned short* wpr_t  = (unsigned short*)alloc((size_t)1024 * 4096 * 2);
    unsigned short* h1     = (unsigned short*)alloc((size_t)MTOK * Cz * 2);
    unsigned short* qbuf   = (unsigned short*)alloc((size_t)MTOK * Cz * 2);
    unsigned short* kbuf   = (unsigned short*)alloc((size_t)MTOK * Cz * 2);
    unsigned short* vbuf   = (unsigned short*)alloc((size_t)MTOK * Cz * 2);   // vt [B,H,D,T]
    unsigned short* ybuf   = (unsigned short*)alloc((size_t)MTOK * Cz * 2);
    float*          x1     = (float*)alloc((size_t)MTOK * Cz * 4);
    unsigned short* h2     = (unsigned short*)alloc((size_t)MTOK * Cz * 2);
    unsigned short* fbuf   = (unsigned short*)alloc((size_t)MTOK * 4096 * 2);
    // vtmp ([B,H,T,D] V before transpose) aliases fbuf: lifetimes disjoint
    unsigned short* vtmp   = fbuf;

    dim3 tb(32, 8);
    transpose_w<<<dim3(3072 / 32, 1024 / 32), tb, 0, stream>>>(Wqkv, wqkv_t, 1024, 3072);
    transpose_w<<<dim3(1024 / 32, 1024 / 32), tb, 0, stream>>>(Wo, wo_t, 1024, 1024);
    transpose_w<<<dim3(4096 / 32, 1024 / 32), tb, 0, stream>>>(Wfc, wfc_t, 1024, 4096);
    transpose_w<<<dim3(1024 / 32, 4096 / 32), tb, 0, stream>>>(Wpr, wpr_t, 4096, 1024);

    ln_kernel<<<MTOK, 256, 0, stream>>>(x, ln1g, ln1b, h1);
    // QKV: M=8192, K=1024, N=3072 -> 32m x 24n = 768 blocks (3 clean rounds)
    gemm_p<MODE_QKV><<<768, 512, 0, stream>>>(h1, wqkv_t, 1024, 1024, 3072, bqkv,
                                              nullptr, nullptr, nullptr, qbuf, kbuf, vtmp);
    transpose_v<<<dim3(64, 32), 256, 0, stream>>>(vtmp, vbuf);
    attn_kernel<<<1024, 256, 0, stream>>>(qbuf, kbuf, vbuf, ybuf);
    // O-proj: N=1024 -> 256 blocks (1 round)
    gemm_p<MODE_RESID><<<256, 512, 0, stream>>>(ybuf, wo_t, 1024, 1024, 1024, bo,
                                                x1, nullptr, x, nullptr, nullptr, nullptr);
    ln_kernel<<<MTOK, 256, 0, stream>>>(x1, ln2g, ln2b, h2);
    // FC: M=8192, K=1024, N=4096 -> 32m x 32n = 1024 blocks (4 clean rounds)
    gemm_p<MODE_GELU><<<1024, 512, 0, stream>>>(h2, wfc_t, 1024, 1024, 4096, bfc,
                                                nullptr, fbuf, nullptr, nullptr, nullptr, nullptr);
    // PR: M=8192, K=4096, N=1024 -> 256 blocks (1 round)
    gemm_p<MODE_RESID><<<256, 512, 0, stream>>>(fbuf, wpr_t, 4096, 4096, 1024, bpr,
                                                out, nullptr, x1, nullptr, nullptr, nullptr);
}

// Round 6
// 516.147 us; speedup vs baseline: 1.0032x; 1.0032x over previous
//
#include <hip/hip_runtime.h>
#include <math.h>
#include <stdint.h>

#define Bz 4
#define Tz 2048
#define Cz 1024
#define Hz 16
#define Dz 64
#define MTOK (Bz*Tz)   // 8192

typedef __attribute__((ext_vector_type(8))) short short8;
typedef __attribute__((ext_vector_type(4))) short short4v;
typedef __attribute__((ext_vector_type(4))) float f32x4;

typedef unsigned int u32_g __attribute__((address_space(1)));
typedef unsigned int u32_l __attribute__((address_space(3)));

__device__ __forceinline__ unsigned short f2bf(float f) {
    unsigned int u = __float_as_uint(f);
    u += 0x7fffu + ((u >> 16) & 1u);
    return (unsigned short)(u >> 16);
}
__device__ __forceinline__ float bf2f(unsigned short h) {
    return __uint_as_float((unsigned int)h << 16);
}

__device__ __forceinline__ void async_cp16(const unsigned short* g, unsigned short* l) {
    __builtin_amdgcn_global_load_lds((const u32_g*)g, (u32_l*)l, 16, 0, 0);
}

// s_barrier WITH memory clobber: also fences memory-op motion (plain builtin
// s_barrier does not stop the compiler hoisting LDS reads above it).
#define BARX() asm volatile("s_barrier" ::: "memory")
#define VMCM(n) asm volatile("s_waitcnt vmcnt(" #n ")" ::: "memory")

// ---- weight prep: W[K][N] f32 -> Bf fragment-ordered bf16 ----------------------
// Fragment (nf, kt): 16 cols x 32 k. lane l: col nf*16+(l&15), k kt*32+(l>>4)*8..+8
// stored at Bf[((nf*KT + kt)*64 + l)*8 .. +8]. A wave's B-frag load is then ONE
// perfectly-coalesced global_load_dwordx4 (lane*16B), no LDS involved.
__global__ void transpose_wf(const float* __restrict__ W, unsigned short* __restrict__ Bf,
                             int K, int N) {
    const int nf = blockIdx.x;
    const int k0 = blockIdx.y * 128;
    const int tid = threadIdx.x;          // 256
    const int ktl = tid >> 6, lane = tid & 63;
    const int col = nf * 16 + (lane & 15);
    const int kk = k0 + ktl * 32 + (lane >> 4) * 8;
    const int KT = K >> 5;
    short8 o;
    #pragma unroll
    for (int j = 0; j < 8; j++)
        o[j] = (short)f2bf(W[(size_t)(kk + j) * N + col]);
    *(short8*)&Bf[(((size_t)nf * KT + (k0 >> 5) + ktl) * 64 + lane) * 8] = o;
}

// ---------------- V transpose: vtmp[B*H][T][D] -> vt[B*H][D][T] -----------------
__global__ void transpose_v(const unsigned short* __restrict__ in, unsigned short* __restrict__ out) {
    __shared__ unsigned short tile[64][68];
    const int bh = blockIdx.x;
    const int t0 = blockIdx.y * 64;
    const int tid = threadIdx.x;
    const int r4 = tid >> 4;
    const int c4 = tid & 15;
    #pragma unroll
    for (int p = 0; p < 4; p++) {
        const int r = p * 16 + r4;
        *(short4v*)&tile[r][c4 * 4] =
            *(const short4v*)&in[((size_t)bh * Tz + t0 + r) * Dz + c4 * 4];
    }
    __syncthreads();
    #pragma unroll
    for (int p = 0; p < 4; p++) {
        const int d = p * 16 + r4;
        short4v o;
        #pragma unroll
        for (int j = 0; j < 4; j++) o[j] = tile[c4 * 4 + j][d];
        *(short4v*)&out[((size_t)bh * Dz + d) * Tz + t0 + c4 * 4] = o;
    }
}

// ---------------- layernorm: fp32 in -> bf16 out ----------------
__global__ void ln_kernel(const float* __restrict__ x, const float* __restrict__ g,
                          const float* __restrict__ bb, unsigned short* __restrict__ out) {
    int tok = blockIdx.x, tid = threadIdx.x;
    const float4 v = ((const float4*)(x + (size_t)tok * Cz))[tid];
    float s = v.x + v.y + v.z + v.w;
    float sq = v.x * v.x + v.y * v.y + v.z * v.z + v.w * v.w;
    #pragma unroll
    for (int m = 1; m < 64; m <<= 1) { s += __shfl_xor(s, m); sq += __shfl_xor(sq, m); }
    __shared__ float red[8];
    int lane = tid & 63, wid = tid >> 6;
    if (!lane) { red[wid] = s; red[4 + wid] = sq; }
    __syncthreads();
    s = red[0] + red[1] + red[2] + red[3];
    sq = red[4] + red[5] + red[6] + red[7];
    float mu = s * (1.0f / Cz);
    float var = sq * (1.0f / Cz) - mu * mu;
    float rs = rsqrtf(var + 1e-5f);
    float4 gv = ((const float4*)g)[tid];
    float4 bv = ((const float4*)bb)[tid];
    short4v o;
    o[0] = f2bf((v.x - mu) * rs * gv.x + bv.x);
    o[1] = f2bf((v.y - mu) * rs * gv.y + bv.y);
    o[2] = f2bf((v.z - mu) * rs * gv.z + bv.z);
    o[3] = f2bf((v.w - mu) * rs * gv.w + bv.w);
    *(short4v*)(out + (size_t)tok * Cz + tid * 4) = o;
}

#define MODE_QKV 0
#define MODE_RESID 1
#define MODE_GELU 2

// ========== GEMM: A via LDS, B via fragment-ordered DIRECT global loads =========
// BM = 2*WM, BN = 256. 512 thr = 8 waves (2M x 4N), wave tile WM x 64.
// LDS holds ONLY A: 4 slots x BM*32 bf16 (32/64 KiB), stage depth 3 via
// global_load_lds. B-fragments load straight to VGPRs (asm-pinned
// global_load_dwordx4, issued one K-tile ahead, double-set bfP/bfQ).
// Per K-tile: 1 counted vmcnt + 1 barrier. Queue at body t's wait:
// [A(t+1):a, B(t):4, A(t+2):a] -> vmcnt(a) retires A..t+1 and B(t).
// Drain-0 only for t >= NT-2. LDS pipe/tile: 32-64KB (385-770 clk) vs MFMA
// 620-1240 clk -> LDS no longer the binding pipe.
template <int MODE, int WM>
__launch_bounds__(512, 1)
__global__ void gemm_bg(const unsigned short* __restrict__ A, const unsigned short* __restrict__ Bf,
                        int K, int N, const float* __restrict__ bias,
                        float* __restrict__ outf, unsigned short* __restrict__ outb,
                        const float* __restrict__ resid,
                        unsigned short* __restrict__ qo, unsigned short* __restrict__ ko,
                        unsigned short* __restrict__ vo) {
    constexpr int MI = WM / 16;            // A-frags per wave: 4 or 8
    constexpr int BM = 2 * WM;             // 128 or 256
    constexpr int SLOT = BM * 32;          // shorts per LDS slot
    constexpr int AC = BM / 128;           // cp16 per thread per stage: 1 or 2
    constexpr int MT = 8192 / BM;          // m-tiles (64 or 32)
    constexpr int MT8 = MT / 8;
    __shared__ __align__(16) unsigned short LDS[4 * SLOT];

    const int tid = threadIdx.x;
    const int lane = tid & 63;
    const int wid = tid >> 6;
    const int quad = lane >> 4, l15 = lane & 15;
    const int gm = wid >> 2, gn = wid & 3;
    const int id = blockIdx.x;
    const int rr = id >> 3;
    const int m0 = ((id & 7) * MT8 + (rr % MT8)) * BM;   // XCD owns contiguous m-tiles
    const int n0 = (rr / MT8) * 256;
    const int NT = K >> 5;
    const int KT = K >> 5;

    // A staging: thread -> row tid/4 (+128 for BM256), phys seg tid&3, source col
    // pre-swizzled (seg ^ (row>>1)&3) so linear LDS dest + swizzled read match.
    const int lseg = (tid & 3) ^ ((tid >> 3) & 3);
    const int srow = tid >> 2;
    const unsigned short* Ag0 = A + (size_t)(m0 + srow) * K + lseg * 8;
    const unsigned short* Ag1 = A + (size_t)(m0 + 128 + srow) * K + lseg * 8;

    int offA[MI];
    #pragma unroll
    for (int mi = 0; mi < MI; mi++) {
        const int ra = gm * WM + mi * 16 + l15;
        offA[mi] = ra * 32 + ((quad ^ ((ra >> 1) & 3)) << 3);
    }

    // B fragment pointers: frag (nfg+ni), kt -> Bf + ((nfg+ni)*KT + kt)*512 + lane*8
    const int nfg = (n0 >> 4) + gn * 4;
    const unsigned short* Bp[4];
    #pragma unroll
    for (int ni = 0; ni < 4; ni++)
        Bp[ni] = Bf + ((size_t)(nfg + ni) * KT) * 512 + lane * 8;

    f32x4 acc[MI][4] = {};
    short8 af[MI], bfP[4], bfQ[4];

#define GLB(bfX) do { _Pragma("unroll") for (int ni = 0; ni < 4; ni++) { \
    asm volatile("global_load_dwordx4 %0, %1, off" \
        : "=&v"(bfX[ni]) : "v"((unsigned long long)(uintptr_t)Bp[ni]) : "memory"); \
    Bp[ni] += 512; } } while (0)
#define STG(tt) do { unsigned short* sp_ = LDS + (((unsigned)(tt)) & 3u) * SLOT; \
    const size_t kof_ = (size_t)(tt) * 32; \
    async_cp16(Ag0 + kof_, sp_ + tid * 8); \
    if constexpr (AC == 2) async_cp16(Ag1 + kof_, sp_ + 4096 + tid * 8); } while (0)
#define RDS(tt) do { const unsigned short* sp_ = LDS + (((unsigned)(tt)) & 3u) * SLOT; \
    _Pragma("unroll") for (int mi = 0; mi < MI; mi++) af[mi] = *(const short8*)(sp_ + offA[mi]); } while (0)
#define MMS(bfX) do { \
    __builtin_amdgcn_s_setprio(1); \
    _Pragma("unroll") for (int mi = 0; mi < MI; mi++) \
        _Pragma("unroll") for (int ni = 0; ni < 4; ni++) \
            acc[mi][ni] = __builtin_amdgcn_mfma_f32_16x16x32_bf16(af[mi], bfX[ni], acc[mi][ni], 0, 0, 0); \
    __builtin_amdgcn_s_setprio(0); } while (0)
#define WAITV(tt) do { \
    if ((tt) == 0)            { if constexpr (AC == 2) VMCM(4); else VMCM(2); } \
    else if ((tt) >= NT - 2)  { VMCM(0); } \
    else                      { if constexpr (AC == 2) VMCM(2); else VMCM(1); } } while (0)

    // prologue: B(0) then A stages 0..2 (order fixes the vmcnt queue math)
    GLB(bfP);
    STG(0); STG(1); STG(2);

    for (int t = 0; t < NT; t += 2) {
        // even body: consume tile t (bfP), prefetch B(t+1) and A(t+3)
        WAITV(t);
        BARX();
        if (t + 1 < NT) GLB(bfQ);
        if (t + 3 < NT) STG(t + 3);
        RDS(t);
        MMS(bfP);
        // odd body: consume tile t+1 (bfQ), prefetch B(t+2) and A(t+4)
        WAITV(t + 1);
        BARX();
        if (t + 2 < NT) GLB(bfP);
        if (t + 4 < NT) STG(t + 4);
        RDS(t + 1);
        MMS(bfQ);
    }
#undef GLB
#undef STG
#undef RDS
#undef MMS
#undef WAITV

    // epilogue: ni innermost (full 128B output lines -> no write amplification)
    float bv[4];
    #pragma unroll
    for (int ni = 0; ni < 4; ni++) bv[ni] = bias[n0 + gn * 64 + ni * 16 + l15];

    if constexpr (MODE == MODE_QKV) {
        const int colb = n0 + gn * 64;          // 64-aligned -> one (which, head)
        const int which = colb >> 10;
        const int hh = (colb & 1023) >> 6;
        unsigned short* dst = (which == 0) ? qo : (which == 1) ? ko : vo;
        #pragma unroll
        for (int mi = 0; mi < MI; mi++) {
            #pragma unroll
            for (int r = 0; r < 4; r++) {
                const int row = m0 + gm * WM + mi * 16 + quad * 4 + r;
                const int b_ = row >> 11, tt = row & 2047;
                unsigned short* rp = dst + ((size_t)(b_ * Hz + hh) * Tz + tt) * Dz;
                #pragma unroll
                for (int ni = 0; ni < 4; ni++)
                    rp[ni * 16 + l15] = f2bf(acc[mi][ni][r] + bv[ni]);
            }
        }
    } else if constexpr (MODE == MODE_RESID) {
        #pragma unroll
        for (int mi = 0; mi < MI; mi++) {
            #pragma unroll
            for (int r = 0; r < 4; r++) {
                const int row = m0 + gm * WM + mi * 16 + quad * 4 + r;
                float* rp = outf + (size_t)row * N + n0 + gn * 64;
                const float* rr_ = resid + (size_t)row * N + n0 + gn * 64;
                #pragma unroll
                for (int ni = 0; ni < 4; ni++) {
                    const int c = ni * 16 + l15;
                    rp[c] = acc[mi][ni][r] + bv[ni] + rr_[c];
                }
            }
        }
    } else {  // MODE_GELU, tanh-form
        #pragma unroll
        for (int mi = 0; mi < MI; mi++) {
            #pragma unroll
            for (int r = 0; r < 4; r++) {
                const int row = m0 + gm * WM + mi * 16 + quad * 4 + r;
                unsigned short* rp = outb + (size_t)row * N + n0 + gn * 64;
                #pragma unroll
                for (int ni = 0; ni < 4; ni++) {
                    float val = acc[mi][ni][r] + bv[ni];
                    float c = val * (1.0f + 0.044715f * val * val);
                    float e = __expf(1.5957691216057308f * c);
                    rp[ni * 16 + l15] = f2bf(val * e / (1.0f + e));
                }
            }
        }
    }
}

// ---------------- causal flash attention, bf16 MFMA ----------------
#define ATT_SC 0.18033688011112042f   // 0.125 * log2(e)
__launch_bounds__(256)
__global__ void attn_kernel(const unsigned short* __restrict__ qb, const unsigned short* __restrict__ kb,
                            const unsigned short* __restrict__ vt, unsigned short* __restrict__ y) {
    __shared__ __align__(16) unsigned short Klds[64 * 64];
    __shared__ __align__(16) unsigned short Vtl[64 * 64];
    __shared__ __align__(16) unsigned short Plds[4][16 * 72];
    const int tid = threadIdx.x;
    const int lane = tid & 63, wid = tid >> 6;
    const int quad = lane >> 4, l15 = lane & 15;
    const int bh = blockIdx.x & 63;
    const int qt = 15 - (int)(blockIdx.x >> 6);
    const size_t baseT = (size_t)bh * Tz;
    const size_t vbase = (size_t)bh * Dz;
    const int qb0 = qt * 128;

    short8 qf[2][2];
    {
        const unsigned short* q0p = qb + (baseT + qb0 + wid * 16 + l15) * Dz + quad * 8;
        qf[0][0] = *(const short8*)q0p;
        qf[0][1] = *(const short8*)(q0p + 32);
        const unsigned short* q1p = q0p + (size_t)64 * Dz;
        qf[1][0] = *(const short8*)q1p;
        qf[1][1] = *(const short8*)(q1p + 32);
    }

    f32x4 o[2][4] = {};
    float lsum[2][4] = {{0.f,0.f,0.f,0.f},{0.f,0.f,0.f,0.f}};

    const int srow = lane >> 3;
    const int swz = ((lane & 7) ^ srow) * 8;
    const unsigned short* kg0 = kb + (baseT + wid * 8 + srow) * Dz + swz;
    const unsigned short* kg1 = kg0 + (size_t)32 * Dz;
    const unsigned short* vg0 = vt + (vbase + wid * 8 + srow) * Tz + swz;
    const unsigned short* vg1 = vg0 + (size_t)32 * Tz;
    unsigned short* kl0 = &Klds[wid * 512 + lane * 8];
    unsigned short* kl1 = kl0 + 2048;
    unsigned short* vl0 = &Vtl[wid * 512 + lane * 8];
    unsigned short* vl1 = vl0 + 2048;

    const int nchunk = 2 * qt + 2;

    for (int ci = 0; ci < nchunk; ci++) {
        const int k0 = ci * 64;
        async_cp16(kg0 + (size_t)k0 * Dz, kl0);
        async_cp16(kg1 + (size_t)k0 * Dz, kl1);
        async_cp16(vg0 + k0, vl0);
        async_cp16(vg1 + k0, vl1);
        __syncthreads();

        #pragma unroll
        for (int t = 0; t < 2; t++) {
            if (t == 0 && ci == nchunk - 1) continue;
            const bool diag = (ci == nchunk - 2 + t);

            f32x4 s[4];
            #pragma unroll
            for (int c = 0; c < 4; c++) {
                const int rk = c * 16 + l15;
                short8 kf0 = *(const short8*)&Klds[rk * 64 + ((quad ^ (rk & 7)) * 8)];
                short8 kf1 = *(const short8*)&Klds[rk * 64 + (((quad + 4) ^ (rk & 7)) * 8)];
                f32x4 z = {};
                z = __builtin_amdgcn_mfma_f32_16x16x32_bf16(qf[t][0], kf0, z, 0, 0, 0);
                s[c] = __builtin_amdgcn_mfma_f32_16x16x32_bf16(qf[t][1], kf1, z, 0, 0, 0);
            }
            const int qr = qb0 + t * 64 + wid * 16 + quad * 4;
            #pragma unroll
            for (int c = 0; c < 4; c++)
                #pragma unroll
                for (int r = 0; r < 4; r++) {
                    float p = exp2f(s[c][r] * ATT_SC);
                    if (diag) {
                        int key = k0 + c * 16 + l15;
                        p = (key <= qr + r) ? p : 0.f;
                    }
                    s[c][r] = p;
                    lsum[t][r] += p;
                }
            unsigned short* P = Plds[wid];
            #pragma unroll
            for (int c = 0; c < 4; c++)
                #pragma unroll
                for (int r = 0; r < 4; r++)
                    P[(quad * 4 + r) * 72 + c * 16 + l15] = f2bf(s[c][r]);
            short8 pf0 = *(const short8*)&P[l15 * 72 + quad * 8];
            short8 pf1 = *(const short8*)&P[l15 * 72 + 32 + quad * 8];
            #pragma unroll
            for (int nc = 0; nc < 4; nc++) {
                const int rv = nc * 16 + l15;
                short8 vf0 = *(const short8*)&Vtl[rv * 64 + ((quad ^ (rv & 7)) * 8)];
                short8 vf1 = *(const short8*)&Vtl[rv * 64 + (((quad + 4) ^ (rv & 7)) * 8)];
                o[t][nc] = __builtin_amdgcn_mfma_f32_16x16x32_bf16(pf0, vf0, o[t][nc], 0, 0, 0);
                o[t][nc] = __builtin_amdgcn_mfma_f32_16x16x32_bf16(pf1, vf1, o[t][nc], 0, 0, 0);
            }
        }
        __syncthreads();
    }

    const int b_ = bh >> 4, hh = bh & 15;
    #pragma unroll
    for (int t = 0; t < 2; t++)
        #pragma unroll
        for (int r = 0; r < 4; r++) {
            float ls = lsum[t][r];
            #pragma unroll
            for (int m = 1; m < 16; m <<= 1) ls += __shfl_xor(ls, m);
            float inv = 1.0f / ls;
            size_t tok = (size_t)qb0 + t * 64 + wid * 16 + quad * 4 + r;
            unsigned short* yr = y + ((size_t)b_ * Tz + tok) * Cz + hh * Dz;
            #pragma unroll
            for (int nc = 0; nc < 4; nc++)
                yr[nc * 16 + l15] = f2bf(o[t][nc][r] * inv);
        }
}

extern "C" void kernel_launch(void* const* d_in, const int* in_sizes, int n_in,
                              void* d_out, int out_size, void* d_ws, size_t ws_size,
                              hipStream_t stream) {
    const float* x    = (const float*)d_in[0];
    const float* ln1g = (const float*)d_in[1];
    const float* ln1b = (const float*)d_in[2];
    const float* Wqkv = (const float*)d_in[3];
    const float* bqkv = (const float*)d_in[4];
    const float* Wo   = (const float*)d_in[5];
    const float* bo   = (const float*)d_in[6];
    const float* ln2g = (const float*)d_in[7];
    const float* ln2b = (const float*)d_in[8];
    const float* Wfc  = (const float*)d_in[9];
    const float* bfc  = (const float*)d_in[10];
    const float* Wpr  = (const float*)d_in[11];
    const float* bpr  = (const float*)d_in[12];
    float* out = (float*)d_out;

    char* ws = (char*)d_ws;
    size_t off = 0;
    auto alloc = [&](size_t bytes) { void* p = ws + off; off += (bytes + 255) & ~(size_t)255; return p; };
    unsigned short* wqkv_t = (unsigned short*)alloc((size_t)3072 * 1024 * 2);
    unsigned short* wo_t   = (unsigned short*)alloc((size_t)1024 * 1024 * 2);
    unsigned short* wfc_t  = (unsigned short*)alloc((size_t)4096 * 1024 * 2);
    unsigned short* wpr_t  = (unsigned short*)alloc((size_t)1024 * 4096 * 2);
    unsigned short* h1     = (unsigned short*)alloc((size_t)MTOK * Cz * 2);
    unsigned short* qbuf   = (unsigned short*)alloc((size_t)MTOK * Cz * 2);
    unsigned short* kbuf   = (unsigned short*)alloc((size_t)MTOK * Cz * 2);
    unsigned short* vbuf   = (unsigned short*)alloc((size_t)MTOK * Cz * 2);   // vt [B,H,D,T]
    unsigned short* ybuf   = (unsigned short*)alloc((size_t)MTOK * Cz * 2);
    float*          x1     = (float*)alloc((size_t)MTOK * Cz * 4);
    unsigned short* h2     = (unsigned short*)alloc((size_t)MTOK * Cz * 2);
    unsigned short* fbuf   = (unsigned short*)alloc((size_t)MTOK * 4096 * 2);
    // vtmp ([B,H,T,D] V before transpose) aliases fbuf: lifetimes disjoint
    unsigned short* vtmp   = fbuf;

    // weight prep -> fragment-ordered bf16
    transpose_wf<<<dim3(3072 / 16, 1024 / 128), 256, 0, stream>>>(Wqkv, wqkv_t, 1024, 3072);
    transpose_wf<<<dim3(1024 / 16, 1024 / 128), 256, 0, stream>>>(Wo, wo_t, 1024, 1024);
    transpose_wf<<<dim3(4096 / 16, 1024 / 128), 256, 0, stream>>>(Wfc, wfc_t, 1024, 4096);
    transpose_wf<<<dim3(1024 / 16, 4096 / 128), 256, 0, stream>>>(Wpr, wpr_t, 4096, 1024);

    ln_kernel<<<MTOK, 256, 0, stream>>>(x, ln1g, ln1b, h1);
    // QKV: BM=128, BN=256 -> 64m x 12n = 768 blocks (3 rounds)
    gemm_bg<MODE_QKV, 64><<<768, 512, 0, stream>>>(h1, wqkv_t, 1024, 3072, bqkv,
                                                   nullptr, nullptr, nullptr, qbuf, kbuf, vtmp);
    transpose_v<<<dim3(64, 32), 256, 0, stream>>>(vtmp, vbuf);
    attn_kernel<<<1024, 256, 0, stream>>>(qbuf, kbuf, vbuf, ybuf);
    // O-proj: BM=128, BN=256 -> 64m x 4n = 256 blocks (1 round)
    gemm_bg<MODE_RESID, 64><<<256, 512, 0, stream>>>(ybuf, wo_t, 1024, 1024, bo,
                                                     x1, nullptr, x, nullptr, nullptr, nullptr);
    ln_kernel<<<MTOK, 256, 0, stream>>>(x1, ln2g, ln2b, h2);
    // FC: BM=256, BN=256 -> 32m x 16n = 512 blocks (2 rounds)
    gemm_bg<MODE_GELU, 128><<<512, 512, 0, stream>>>(h2, wfc_t, 1024, 4096, bfc,
                                                     nullptr, fbuf, nullptr, nullptr, nullptr, nullptr);
    // PR: BM=128, BN=256, K=4096 -> 64m x 4n = 256 blocks (1 round)
    gemm_bg<MODE_RESID, 64><<<256, 512, 0, stream>>>(fbuf, wpr_t, 4096, 1024, bpr,
                                                     out, nullptr, x1, nullptr, nullptr, nullptr);
}

// Round 9
// 499.839 us; speedup vs baseline: 1.0359x; 1.0326x over previous
//
#include <hip/hip_runtime.h>
#include <math.h>
#include <stdint.h>

#define Bz 4
#define Tz 2048
#define Cz 1024
#define Hz 16
#define Dz 64
#define MTOK (Bz*Tz)   // 8192

typedef __attribute__((ext_vector_type(8))) short short8;
typedef __attribute__((ext_vector_type(4))) short short4v;
typedef __attribute__((ext_vector_type(4))) float f32x4;

typedef unsigned int u32_g __attribute__((address_space(1)));
typedef unsigned int u32_l __attribute__((address_space(3)));

__device__ __forceinline__ unsigned short f2bf(float f) {
    unsigned int u = __float_as_uint(f);
    u += 0x7fffu + ((u >> 16) & 1u);
    return (unsigned short)(u >> 16);
}
__device__ __forceinline__ float bf2f(unsigned short h) {
    return __uint_as_float((unsigned int)h << 16);
}

__device__ __forceinline__ void async_cp16(const unsigned short* g, unsigned short* l) {
    __builtin_amdgcn_global_load_lds((const u32_g*)g, (u32_l*)l, 16, 0, 0);
}

#define BARX() asm volatile("s_barrier" ::: "memory")
#define VMCM(n) asm volatile("s_waitcnt vmcnt(" #n ")" ::: "memory")
#define LGKMC(n) do { asm volatile("s_waitcnt lgkmcnt(" #n ")" ::: "memory"); \
                      __builtin_amdgcn_sched_barrier(0); } while (0)

// ---- weight prep: W[K][N] f32 -> Bf fragment-ordered bf16 ----------------------
// Fragment (nf, kt): 16 cols x 32 k. lane l: col nf*16+(l&15), k kt*32+(l>>4)*8..+8
// stored at Bf[((nf*KT + kt)*64 + l)*8 .. +8] -> one coalesced dwordx4 per frag.
__global__ void transpose_wf(const float* __restrict__ W, unsigned short* __restrict__ Bf,
                             int K, int N) {
    const int nf = blockIdx.x;
    const int k0 = blockIdx.y * 128;
    const int tid = threadIdx.x;          // 256
    const int ktl = tid >> 6, lane = tid & 63;
    const int col = nf * 16 + (lane & 15);
    const int kk = k0 + ktl * 32 + (lane >> 4) * 8;
    const int KT = K >> 5;
    short8 o;
    #pragma unroll
    for (int j = 0; j < 8; j++)
        o[j] = (short)f2bf(W[(size_t)(kk + j) * N + col]);
    *(short8*)&Bf[(((size_t)nf * KT + (k0 >> 5) + ktl) * 64 + lane) * 8] = o;
}

// ---------------- V transpose: vtmp[B*H][T][D] -> vt[B*H][D][T] -----------------
__global__ void transpose_v(const unsigned short* __restrict__ in, unsigned short* __restrict__ out) {
    __shared__ unsigned short tile[64][68];
    const int bh = blockIdx.x;
    const int t0 = blockIdx.y * 64;
    const int tid = threadIdx.x;
    const int r4 = tid >> 4;
    const int c4 = tid & 15;
    #pragma unroll
    for (int p = 0; p < 4; p++) {
        const int r = p * 16 + r4;
        *(short4v*)&tile[r][c4 * 4] =
            *(const short4v*)&in[((size_t)bh * Tz + t0 + r) * Dz + c4 * 4];
    }
    __syncthreads();
    #pragma unroll
    for (int p = 0; p < 4; p++) {
        const int d = p * 16 + r4;
        short4v o;
        #pragma unroll
        for (int j = 0; j < 4; j++) o[j] = tile[c4 * 4 + j][d];
        *(short4v*)&out[((size_t)bh * Dz + d) * Tz + t0 + c4 * 4] = o;
    }
}

// ---------------- layernorm: fp32 in -> bf16 out ----------------
__global__ void ln_kernel(const float* __restrict__ x, const float* __restrict__ g,
                          const float* __restrict__ bb, unsigned short* __restrict__ out) {
    int tok = blockIdx.x, tid = threadIdx.x;
    const float4 v = ((const float4*)(x + (size_t)tok * Cz))[tid];
    float s = v.x + v.y + v.z + v.w;
    float sq = v.x * v.x + v.y * v.y + v.z * v.z + v.w * v.w;
    #pragma unroll
    for (int m = 1; m < 64; m <<= 1) { s += __shfl_xor(s, m); sq += __shfl_xor(sq, m); }
    __shared__ float red[8];
    int lane = tid & 63, wid = tid >> 6;
    if (!lane) { red[wid] = s; red[4 + wid] = sq; }
    __syncthreads();
    s = red[0] + red[1] + red[2] + red[3];
    sq = red[4] + red[5] + red[6] + red[7];
    float mu = s * (1.0f / Cz);
    float var = sq * (1.0f / Cz) - mu * mu;
    float rs = rsqrtf(var + 1e-5f);
    float4 gv = ((const float4*)g)[tid];
    float4 bv = ((const float4*)bb)[tid];
    short4v o;
    o[0] = f2bf((v.x - mu) * rs * gv.x + bv.x);
    o[1] = f2bf((v.y - mu) * rs * gv.y + bv.y);
    o[2] = f2bf((v.z - mu) * rs * gv.z + bv.z);
    o[3] = f2bf((v.w - mu) * rs * gv.w + bv.w);
    *(short4v*)(out + (size_t)tok * Cz + tid * 4) = o;
}

#define MODE_QKV 0
#define MODE_RESID 1
#define MODE_GELU 2

// ========== register-pipelined GEMM: BM=64 x BN=256, BK=32, 256 thr =============
// 4 waves (1M x 4N), per-wave tile 64x64. LDS: 4 slots x 64x32 A only (16 KiB)
// -> ~3 blocks/CU cross-block TLP. B direct-to-VGPR from fragment-ordered
// weights, lookahead 2. A-frags prefetched 1 tile ahead via INLINE-ASM
// ds_read_b128 into named double sets (un-sinkable). lgkmcnt(4) before each MFMA
// cluster waits only the PREVIOUS body's reads. vmcnt(5) steady.
// Prologue order STG0,STG1,B0,B1,STG2 + VMCM(5) leaves queue [bfQ*4, STG2] ==
// the loop's steady-state shape; retires STG0,STG1,bfP -> body A(0)'s reads of
// slot1 and MFMA on bfP are covered (fixes the r7 prologue race on slot 1).
template <int MODE>
__launch_bounds__(256)
__global__ void gemm_rp(const unsigned short* __restrict__ A, const unsigned short* __restrict__ Bf,
                        int K, int N, const float* __restrict__ bias,
                        float* __restrict__ outf, unsigned short* __restrict__ outb,
                        const float* __restrict__ resid,
                        unsigned short* __restrict__ qo, unsigned short* __restrict__ ko,
                        unsigned short* __restrict__ vo) {
    __shared__ __align__(16) unsigned short LDS[4 * 2048];   // 16 KiB
    const int tid = threadIdx.x;
    const int lane = tid & 63;
    const int gn = tid >> 6;               // wave = n-group 0..3
    const int quad = lane >> 4, l15 = lane & 15;
    const int id = blockIdx.x;
    const int rr = id >> 3;
    const int m0 = ((id & 7) * 16 + (rr & 15)) * 64;  // same-m across n -> same XCD
    const int n0 = (rr >> 4) * 256;
    const int NT = K >> 5;
    const int KT = K >> 5;

    // A staging: thread -> row tid/4, phys 16B-seg tid&3, source col pre-swizzled
    const int lseg = (tid & 3) ^ ((tid >> 3) & 3);
    const int srow = tid >> 2;
    const unsigned short* Ag0 = A + (size_t)(m0 + srow) * K + lseg * 8;

    const unsigned ldsA = (unsigned)(uintptr_t)(u32_l*)LDS;
    unsigned offAb[4];
    #pragma unroll
    for (int mi = 0; mi < 4; mi++) {
        const int ra = mi * 16 + l15;
        offAb[mi] = (unsigned)(ra * 64 + ((quad ^ ((ra >> 1) & 3)) << 4));
    }

    // B fragment pointers
    const int nfg = (n0 >> 4) + gn * 4;
    const unsigned short* Bp[4];
    #pragma unroll
    for (int ni = 0; ni < 4; ni++)
        Bp[ni] = Bf + ((size_t)(nfg + ni) * KT) * 512 + lane * 8;

    f32x4 acc[4][4] = {};
    short8 afP[4], afQ[4], bfP[4], bfQ[4];

#define GLBa(bfX) do { _Pragma("unroll") for (int ni = 0; ni < 4; ni++) { \
    asm volatile("global_load_dwordx4 %0, %1, off" \
        : "=&v"(bfX[ni]) : "v"((unsigned long long)(uintptr_t)Bp[ni]) : "memory"); \
    Bp[ni] += 512; } } while (0)
#define STG(tt) async_cp16(Ag0 + (size_t)(tt) * 32, LDS + (((unsigned)(tt)) & 3u) * 2048 + tid * 8)
#define RDSa(afX, tt) do { \
    const unsigned sb_ = ldsA + (((unsigned)(tt)) & 3u) * 4096u; \
    _Pragma("unroll") for (int mi = 0; mi < 4; mi++) \
        asm volatile("ds_read_b128 %0, %1" : "=&v"(afX[mi]) : "v"(sb_ + offAb[mi])); } while (0)
#define MMS(afX, bfX) do { \
    __builtin_amdgcn_s_setprio(1); \
    _Pragma("unroll") for (int mi = 0; mi < 4; mi++) \
        _Pragma("unroll") for (int ni = 0; ni < 4; ni++) \
            acc[mi][ni] = __builtin_amdgcn_mfma_f32_16x16x32_bf16(afX[mi], bfX[ni], acc[mi][ni], 0, 0, 0); \
    __builtin_amdgcn_s_setprio(0); } while (0)

    // prologue FIFO: [S0, S1, P*4, Q*4, S2]; VMCM(5) retires S0,S1,P*4
    // -> queue [Q*4, S2] = steady-state shape; slot0/slot1/bfP all covered.
    STG(0); STG(1); GLBa(bfP); GLBa(bfQ); STG(2);
    VMCM(5);
    BARX();
    RDSa(afP, 0);

    for (int t = 0; t < NT; t += 2) {
        // ---- body A: tile t via (afP, bfP) ----
        if (t + 3 < NT) STG(t + 3);
        RDSa(afQ, t + 1);                  // t+1 < NT always (NT even)
        LGKMC(4);                          // waits afP's 4 reads; afQ's stay in flight
        MMS(afP, bfP);
        if (t + 2 < NT) GLBa(bfP);         // B(t+2)
        if (t + 3 < NT) { VMCM(5); } else { VMCM(0); }
        BARX();
        // ---- body B: tile t+1 via (afQ, bfQ) ----
        if (t + 4 < NT) STG(t + 4);
        if (t + 2 < NT) { RDSa(afP, t + 2); LGKMC(4); } else { LGKMC(0); }
        MMS(afQ, bfQ);
        if (t + 3 < NT) GLBa(bfQ);         // B(t+3)
        if (t + 4 < NT) { VMCM(5); } else { VMCM(0); }
        BARX();
    }
#undef GLBa
#undef STG
#undef RDSa
#undef MMS

    // epilogue: ni innermost -> full output lines, no write amplification
    float bv[4];
    #pragma unroll
    for (int ni = 0; ni < 4; ni++) bv[ni] = bias[n0 + gn * 64 + ni * 16 + l15];

    if constexpr (MODE == MODE_QKV) {
        const int colb = n0 + gn * 64;
        const int which = colb >> 10;
        const int hh = (colb & 1023) >> 6;
        unsigned short* dst = (which == 0) ? qo : (which == 1) ? ko : vo;
        #pragma unroll
        for (int mi = 0; mi < 4; mi++) {
            #pragma unroll
            for (int r = 0; r < 4; r++) {
                const int row = m0 + mi * 16 + quad * 4 + r;
                const int b_ = row >> 11, tt = row & 2047;
                unsigned short* rp = dst + ((size_t)(b_ * Hz + hh) * Tz + tt) * Dz;
                #pragma unroll
                for (int ni = 0; ni < 4; ni++)
                    rp[ni * 16 + l15] = f2bf(acc[mi][ni][r] + bv[ni]);
            }
        }
    } else if constexpr (MODE == MODE_RESID) {
        #pragma unroll
        for (int mi = 0; mi < 4; mi++) {
            #pragma unroll
            for (int r = 0; r < 4; r++) {
                const int row = m0 + mi * 16 + quad * 4 + r;
                float* rp = outf + (size_t)row * N + n0 + gn * 64;
                const float* rr_ = resid + (size_t)row * N + n0 + gn * 64;
                #pragma unroll
                for (int ni = 0; ni < 4; ni++) {
                    const int c = ni * 16 + l15;
                    rp[c] = acc[mi][ni][r] + bv[ni] + rr_[c];
                }
            }
        }
    } else {  // MODE_GELU, tanh-form
        #pragma unroll
        for (int mi = 0; mi < 4; mi++) {
            #pragma unroll
            for (int r = 0; r < 4; r++) {
                const int row = m0 + mi * 16 + quad * 4 + r;
                unsigned short* rp = outb + (size_t)row * N + n0 + gn * 64;
                #pragma unroll
                for (int ni = 0; ni < 4; ni++) {
                    float val = acc[mi][ni][r] + bv[ni];
                    float c = val * (1.0f + 0.044715f * val * val);
                    float e = __expf(1.5957691216057308f * c);
                    rp[ni * 16 + l15] = f2bf(val * e / (1.0f + e));
                }
            }
        }
    }
}

// ---------------- causal flash attention, bf16 MFMA (unchanged) ----------------
#define ATT_SC 0.18033688011112042f   // 0.125 * log2(e)
__launch_bounds__(256)
__global__ void attn_kernel(const unsigned short* __restrict__ qb, const unsigned short* __restrict__ kb,
                            const unsigned short* __restrict__ vt, unsigned short* __restrict__ y) {
    __shared__ __align__(16) unsigned short Klds[64 * 64];
    __shared__ __align__(16) unsigned short Vtl[64 * 64];
    __shared__ __align__(16) unsigned short Plds[4][16 * 72];
    const int tid = threadIdx.x;
    const int lane = tid & 63, wid = tid >> 6;
    const int quad = lane >> 4, l15 = lane & 15;
    const int bh = blockIdx.x & 63;
    const int qt = 15 - (int)(blockIdx.x >> 6);
    const size_t baseT = (size_t)bh * Tz;
    const size_t vbase = (size_t)bh * Dz;
    const int qb0 = qt * 128;

    short8 qf[2][2];
    {
        const unsigned short* q0p = qb + (baseT + qb0 + wid * 16 + l15) * Dz + quad * 8;
        qf[0][0] = *(const short8*)q0p;
        qf[0][1] = *(const short8*)(q0p + 32);
        const unsigned short* q1p = q0p + (size_t)64 * Dz;
        qf[1][0] = *(const short8*)q1p;
        qf[1][1] = *(const short8*)(q1p + 32);
    }

    f32x4 o[2][4] = {};
    float lsum[2][4] = {{0.f,0.f,0.f,0.f},{0.f,0.f,0.f,0.f}};

    const int srow = lane >> 3;
    const int swz = ((lane & 7) ^ srow) * 8;
    const unsigned short* kg0 = kb + (baseT + wid * 8 + srow) * Dz + swz;
    const unsigned short* kg1 = kg0 + (size_t)32 * Dz;
    const unsigned short* vg0 = vt + (vbase + wid * 8 + srow) * Tz + swz;
    const unsigned short* vg1 = vg0 + (size_t)32 * Tz;
    unsigned short* kl0 = &Klds[wid * 512 + lane * 8];
    unsigned short* kl1 = kl0 + 2048;
    unsigned short* vl0 = &Vtl[wid * 512 + lane * 8];
    unsigned short* vl1 = vl0 + 2048;

    const int nchunk = 2 * qt + 2;

    for (int ci = 0; ci < nchunk; ci++) {
        const int k0 = ci * 64;
        async_cp16(kg0 + (size_t)k0 * Dz, kl0);
        async_cp16(kg1 + (size_t)k0 * Dz, kl1);
        async_cp16(vg0 + k0, vl0);
        async_cp16(vg1 + k0, vl1);
        __syncthreads();

        #pragma unroll
        for (int t = 0; t < 2; t++) {
            if (t == 0 && ci == nchunk - 1) continue;
            const bool diag = (ci == nchunk - 2 + t);

            f32x4 s[4];
            #pragma unroll
            for (int c = 0; c < 4; c++) {
                const int rk = c * 16 + l15;
                short8 kf0 = *(const short8*)&Klds[rk * 64 + ((quad ^ (rk & 7)) * 8)];
                short8 kf1 = *(const short8*)&Klds[rk * 64 + (((quad + 4) ^ (rk & 7)) * 8)];
                f32x4 z = {};
                z = __builtin_amdgcn_mfma_f32_16x16x32_bf16(qf[t][0], kf0, z, 0, 0, 0);
                s[c] = __builtin_amdgcn_mfma_f32_16x16x32_bf16(qf[t][1], kf1, z, 0, 0, 0);
            }
            const int qr = qb0 + t * 64 + wid * 16 + quad * 4;
            #pragma unroll
            for (int c = 0; c < 4; c++)
                #pragma unroll
                for (int r = 0; r < 4; r++) {
                    float p = exp2f(s[c][r] * ATT_SC);
                    if (diag) {
                        int key = k0 + c * 16 + l15;
                        p = (key <= qr + r) ? p : 0.f;
                    }
                    s[c][r] = p;
                    lsum[t][r] += p;
                }
            unsigned short* P = Plds[wid];
            #pragma unroll
            for (int c = 0; c < 4; c++)
                #pragma unroll
                for (int r = 0; r < 4; r++)
                    P[(quad * 4 + r) * 72 + c * 16 + l15] = f2bf(s[c][r]);
            short8 pf0 = *(const short8*)&P[l15 * 72 + quad * 8];
            short8 pf1 = *(const short8*)&P[l15 * 72 + 32 + quad * 8];
            #pragma unroll
            for (int nc = 0; nc < 4; nc++) {
                const int rv = nc * 16 + l15;
                short8 vf0 = *(const short8*)&Vtl[rv * 64 + ((quad ^ (rv & 7)) * 8)];
                short8 vf1 = *(const short8*)&Vtl[rv * 64 + (((quad + 4) ^ (rv & 7)) * 8)];
                o[t][nc] = __builtin_amdgcn_mfma_f32_16x16x32_bf16(pf0, vf0, o[t][nc], 0, 0, 0);
                o[t][nc] = __builtin_amdgcn_mfma_f32_16x16x32_bf16(pf1, vf1, o[t][nc], 0, 0, 0);
            }
        }
        __syncthreads();
    }

    const int b_ = bh >> 4, hh = bh & 15;
    #pragma unroll
    for (int t = 0; t < 2; t++)
        #pragma unroll
        for (int r = 0; r < 4; r++) {
            float ls = lsum[t][r];
            #pragma unroll
            for (int m = 1; m < 16; m <<= 1) ls += __shfl_xor(ls, m);
            float inv = 1.0f / ls;
            size_t tok = (size_t)qb0 + t * 64 + wid * 16 + quad * 4 + r;
            unsigned short* yr = y + ((size_t)b_ * Tz + tok) * Cz + hh * Dz;
            #pragma unroll
            for (int nc = 0; nc < 4; nc++)
                yr[nc * 16 + l15] = f2bf(o[t][nc][r] * inv);
        }
}

extern "C" void kernel_launch(void* const* d_in, const int* in_sizes, int n_in,
                              void* d_out, int out_size, void* d_ws, size_t ws_size,
                              hipStream_t stream) {
    const float* x    = (const float*)d_in[0];
    const float* ln1g = (const float*)d_in[1];
    const float* ln1b = (const float*)d_in[2];
    const float* Wqkv = (const float*)d_in[3];
    const float* bqkv = (const float*)d_in[4];
    const float* Wo   = (const float*)d_in[5];
    const float* bo   = (const float*)d_in[6];
    const float* ln2g = (const float*)d_in[7];
    const float* ln2b = (const float*)d_in[8];
    const float* Wfc  = (const float*)d_in[9];
    const float* bfc  = (const float*)d_in[10];
    const float* Wpr  = (const float*)d_in[11];
    const float* bpr  = (const float*)d_in[12];
    float* out = (float*)d_out;

    char* ws = (char*)d_ws;
    size_t off = 0;
    auto alloc = [&](size_t bytes) { void* p = ws + off; off += (bytes + 255) & ~(size_t)255; return p; };
    unsigned short* wqkv_t = (unsigned short*)alloc((size_t)3072 * 1024 * 2);
    unsigned short* wo_t   = (unsigned short*)alloc((size_t)1024 * 1024 * 2);
    unsigned short* wfc_t  = (unsigned short*)alloc((size_t)4096 * 1024 * 2);
    unsigned short* wpr_t  = (unsigned short*)alloc((size_t)1024 * 4096 * 2);
    unsigned short* h1     = (unsigned short*)alloc((size_t)MTOK * Cz * 2);
    unsigned short* qbuf   = (unsigned short*)alloc((size_t)MTOK * Cz * 2);
    unsigned short* kbuf   = (unsigned short*)alloc((size_t)MTOK * Cz * 2);
    unsigned short* vbuf   = (unsigned short*)alloc((size_t)MTOK * Cz * 2);   // vt [B,H,D,T]
    unsigned short* ybuf   = (unsigned short*)alloc((size_t)MTOK * Cz * 2);
    float*          x1     = (float*)alloc((size_t)MTOK * Cz * 4);
    unsigned short* h2     = (unsigned short*)alloc((size_t)MTOK * Cz * 2);
    unsigned short* fbuf   = (unsigned short*)alloc((size_t)MTOK * 4096 * 2);
    unsigned short* vtmp   = fbuf;   // disjoint lifetime

    transpose_wf<<<dim3(3072 / 16, 1024 / 128), 256, 0, stream>>>(Wqkv, wqkv_t, 1024, 3072);
    transpose_wf<<<dim3(1024 / 16, 1024 / 128), 256, 0, stream>>>(Wo, wo_t, 1024, 1024);
    transpose_wf<<<dim3(4096 / 16, 1024 / 128), 256, 0, stream>>>(Wfc, wfc_t, 1024, 4096);
    transpose_wf<<<dim3(1024 / 16, 4096 / 128), 256, 0, stream>>>(Wpr, wpr_t, 4096, 1024);

    ln_kernel<<<MTOK, 256, 0, stream>>>(x, ln1g, ln1b, h1);
    // QKV: 128m x 12n = 1536 blocks
    gemm_rp<MODE_QKV><<<1536, 256, 0, stream>>>(h1, wqkv_t, 1024, 3072, bqkv,
                                                nullptr, nullptr, nullptr, qbuf, kbuf, vtmp);
    transpose_v<<<dim3(64, 32), 256, 0, stream>>>(vtmp, vbuf);
    attn_kernel<<<1024, 256, 0, stream>>>(qbuf, kbuf, vbuf, ybuf);
    // O-proj: 128m x 4n = 512 blocks
    gemm_rp<MODE_RESID><<<512, 256, 0, stream>>>(ybuf, wo_t, 1024, 1024, bo,
                                                 x1, nullptr, x, nullptr, nullptr, nullptr);
    ln_kernel<<<MTOK, 256, 0, stream>>>(x1, ln2g, ln2b, h2);
    // FC: 128m x 16n = 2048 blocks
    gemm_rp<MODE_GELU><<<2048, 256, 0, stream>>>(h2, wfc_t, 1024, 4096, bfc,
                                                 nullptr, fbuf, nullptr, nullptr, nullptr, nullptr);
    // PR: K=4096, 128m x 4n = 512 blocks
    gemm_rp<MODE_RESID><<<512, 256, 0, stream>>>(fbuf, wpr_t, 4096, 1024, bpr,
                                                 out, nullptr, x1, nullptr, nullptr, nullptr);
}